// Round 14
// baseline (619.136 us; speedup 1.0000x reference)
//
#include <hip/hip_runtime.h>

#define TT 2048
#define BB 256
#define XX 64
#define HH 128
#define YY 32
#define SSTR 12           // 8 data + 4 pad floats per kg-slice (16B-aligned)
#define HBUF (16 * SSTR)  // 192 floats per h buffer

// Kg=16, J=4, 512 thr = 8 waves = 2/SIMD.  R13 analysis: step 861 cyc =
// overlap{VALU 395, DS-engine ~400} + path; this halves DS (32->16 b128
// reads/CU/step) at constant MAC count (per-thread MACs = J*192/Kg = 48
// invariant).  kg = lane&15 (h[8kg..+8), x[4kg..+4)); jp = lane>>4;
// outputs j0..j0+3 = 4*(w*4+jp)..+3; lane finalizes j0 + (lane&3).
// Reduce: merge-scatter on bits {0,1} (quad_perm 0xB1/0x4E, exact) then
// CYCLIC rotation-sum over bits {2,3}: row_ror:4 + row_ror:8 = full 4-coset
// sum for EITHER ror direction (R5-safe by construction; bits 0,1 preserved
// since +/-4m mod 16).  One tanh tail per thread.
// R3: bias after reduction | R6: waves_per_eu exact pin | R7: pk half-rate |
// R11: don't trade DS for VALU+path | R13: lgkm-only barrier (keep).

typedef float v2f __attribute__((ext_vector_type(2)));
typedef float v4f __attribute__((ext_vector_type(4)));

#define PKFMA(acc, a, b)                                              \
    asm("v_pk_fma_f32 %0, %1, %2, %0 op_sel:[0,0,0] op_sel_hi:[1,1,1]"\
        : "+v"(acc) : "v"(a), "v"(b))

template<int CTRL>
static __device__ __forceinline__ float dpp_mov(float s) {
    return __int_as_float(__builtin_amdgcn_update_dpp(
        0, __float_as_int(s), CTRL, 0xF, 0xF, true));
}

static __device__ __forceinline__ void pin2(v2f& v) {
    asm volatile("" : "+v"(v));
}

// lgkm-only barrier: LDS writes visible, global loads not drained (R13).
static __device__ __forceinline__ void barrier_lgkm() {
    asm volatile("s_waitcnt lgkmcnt(0)" ::: "memory");
    __builtin_amdgcn_s_barrier();
    asm volatile("" ::: "memory");
}

#define LO2(v) __builtin_shufflevector(v, v, 0, 1)
#define HI2(v) __builtin_shufflevector(v, v, 2, 3)

__global__ __launch_bounds__(512)
__attribute__((amdgpu_waves_per_eu(2, 2)))
void rnn_persist_kernel(const float* __restrict__ x,
                        const float* __restrict__ W_ih,
                        const float* __restrict__ W_hh,
                        const float* __restrict__ b_ih,
                        const float* __restrict__ b_hh,
                        const float* __restrict__ W_out,
                        const float* __restrict__ b_out,
                        float* __restrict__ out)
{
    __shared__ __align__(16) float h_lds[2][HBUF];

    const int tid  = threadIdx.x;
    const int b    = blockIdx.x;
    const int w    = tid >> 6;           // 0..7
    const int lane = tid & 63;
    const int kg   = lane & 15;          // k-group, lane bits {0,1,2,3}
    const int jp   = lane >> 4;          // 0..3
    const int j0   = (w * 4 + jp) * 4;   // 0..124, step 4
    const int b0   = lane & 1;
    const int b1   = (lane >> 1) & 1;
    const int o    = lane & 3;           // output this lane finalizes
    const int jw   = j0 + o;
    const int woff = (jw >> 3) * SSTR + (jw & 7);
    const bool writer = (lane & 12) == 0;   // bits 2,3 zero: 16 lanes/wave

    const float SC = 2.8853900817779268f;   // 2*log2(e)

    // ---- weights into registers (48 floats, prescaled), pinned ----
    v2f whh2[4][4];   // per jj: 8 floats of W_hh[j0+jj][8kg..+8)
    v2f wih2[4][2];   // per jj: 4 floats of W_ih[j0+jj][4kg..+4)
    #pragma unroll
    for (int jj = 0; jj < 4; ++jj) {
        const v2f* ph = (const v2f*)(W_hh + (j0 + jj) * HH + kg * 8);
        #pragma unroll
        for (int c = 0; c < 4; ++c) whh2[jj][c] = ph[c] * SC;
        const v2f* pi = (const v2f*)(W_ih + (j0 + jj) * XX + kg * 4);
        #pragma unroll
        for (int c = 0; c < 2; ++c) wih2[jj][c] = pi[c] * SC;
    }
    #pragma unroll
    for (int jj = 0; jj < 4; ++jj) {
        #pragma unroll
        for (int c = 0; c < 4; ++c) pin2(whh2[jj][c]);
        pin2(wih2[jj][0]); pin2(wih2[jj][1]);
    }
    const float bsel = (b_ih[jw] + b_hh[jw]) * SC;   // this lane's output bias

    const float* xg = x + (size_t)b * TT * XX + kg * 4;

    if (tid < HBUF) h_lds[0][tid] = 0.f;

    v4f xa = *(const v4f*)xg;          // x(0)
    v4f xb = *(const v4f*)(xg + XX);   // x(1)
    __syncthreads();

#define STEP(RP, WP, XC)                                                   \
    do {                                                                   \
        const v4f* hp = (const v4f*)&h_lds[RP][kg * SSTR];                 \
        const v4f H0 = hp[0], H1 = hp[1];                                  \
        const v2f h2[4] = { LO2(H0), HI2(H0), LO2(H1), HI2(H1) };          \
        const v2f x2[2] = { LO2(XC), HI2(XC) };                            \
        float s[4];                                                        \
        _Pragma("unroll")                                                  \
        for (int jj = 0; jj < 4; ++jj) {                                   \
            v2f a = {0.f, 0.f};                                            \
            PKFMA(a, wih2[jj][0], x2[0]); PKFMA(a, wih2[jj][1], x2[1]);    \
            PKFMA(a, whh2[jj][0], h2[0]); PKFMA(a, whh2[jj][1], h2[1]);    \
            PKFMA(a, whh2[jj][2], h2[2]); PKFMA(a, whh2[jj][3], h2[3]);    \
            s[jj] = a.x + a.y;                                             \
        }                                                                  \
        /* merge-scatter bit0 (quad_perm xor1, exact) */                   \
        float ul = b0 ? s[1] : s[0];                                       \
        float vl = b0 ? s[0] : s[1];                                       \
        ul += dpp_mov<0xB1>(vl);                                           \
        float uh = b0 ? s[3] : s[2];                                       \
        float vh = b0 ? s[2] : s[3];                                       \
        uh += dpp_mov<0xB1>(vh);                                           \
        /* merge-scatter bit1 (quad_perm xor2, exact) */                   \
        float u  = b1 ? uh : ul;                                           \
        float vv = b1 ? ul : uh;                                           \
        u += dpp_mov<0x4E>(vv);                                            \
        /* cyclic full-sum over bits {2,3}: dir-agnostic by construction */\
        u += dpp_mov<0x124>(u);    /* row_ror:4 */                         \
        u += dpp_mov<0x128>(u);    /* row_ror:8 */                         \
        u += bsel;                 /* bias AFTER reduction (R3) */         \
        const float e  = __builtin_amdgcn_exp2f(u);                        \
        const float hn = fmaf(-2.f, __builtin_amdgcn_rcpf(e + 1.f), 1.f); \
        if (writer) h_lds[WP][woff] = hn;                                  \
        barrier_lgkm();                                                    \
    } while (0)

    for (int t = 0; t < TT; t += 2) {
        STEP(0, 1, xa);
        {   // prefetch x(t+2)
            const int tn = (t + 2 < TT) ? t + 2 : TT - 1;
            xa = *(const v4f*)(xg + (size_t)tn * XX);
        }
        STEP(1, 0, xb);
        {   // prefetch x(t+3)
            const int tn = (t + 3 < TT) ? t + 3 : TT - 1;
            xb = *(const v4f*)(xg + (size_t)tn * XX);
        }
    }
#undef STEP

    // ---- readout: out[b, :] = h_last @ W_out^T + b_out (h in buffer 0) ----
    if (tid < YY) {
        const float* h  = h_lds[0];
        const float* wr = W_out + tid * HH;
        float r0 = 0.f, r1 = 0.f, r2 = 0.f, r3 = 0.f;
        #pragma unroll
        for (int s16 = 0; s16 < 16; ++s16) {   // 16 slices of 8 floats
            #pragma unroll
            for (int c = 0; c < 2; ++c) {
                const float4 wv = *(const float4*)(wr + s16 * 8 + c * 4);
                const float4 hv = *(const float4*)(h + s16 * SSTR + c * 4);
                r0 = fmaf(wv.x, hv.x, r0); r1 = fmaf(wv.y, hv.y, r1);
                r2 = fmaf(wv.z, hv.z, r2); r3 = fmaf(wv.w, hv.w, r3);
            }
        }
        out[b * YY + tid] = b_out[tid] + ((r0 + r1) + (r2 + r3));
    }
}

extern "C" void kernel_launch(void* const* d_in, const int* in_sizes, int n_in,
                              void* d_out, int out_size, void* d_ws, size_t ws_size,
                              hipStream_t stream) {
    const float* x     = (const float*)d_in[0];
    const float* W_ih  = (const float*)d_in[1];
    const float* W_hh  = (const float*)d_in[2];
    const float* b_ih  = (const float*)d_in[3];
    const float* b_hh  = (const float*)d_in[4];
    const float* W_out = (const float*)d_in[5];
    const float* b_out = (const float*)d_in[6];
    float* out = (float*)d_out;

    rnn_persist_kernel<<<BB, 512, 0, stream>>>(x, W_ih, W_hh, b_ih, b_hh,
                                               W_out, b_out, out);
}